// Round 2
// baseline (76.279 us; speedup 1.0000x reference)
//
#include <hip/hip_runtime.h>
#include <hip/hip_bf16.h>

#define M_DIM 500000
#define NPER  21
#define NELEM (M_DIM * NPER)     // 10,500,000 floats per (tensor, group)
#define NF4   (NELEM / 4)        // 2,625,000 float4s
#define NBLK  256
#define TPB   252                // block reads 1008 contiguous floats/iter; 1008 % 21 == 0
#define STRIDE (NBLK * TPB)      // 64512 float4s; 4*STRIDE % 21 == 0
#define DM    ((4 * STRIDE) / 21)  // 12288: m advance per grid-stride step

__device__ __forceinline__ float fast_sigmoid(float x) {
    // 1/(1+exp(-x)) with hw rcp approximation (plenty of accuracy vs 0.84 threshold)
    return __builtin_amdgcn_rcpf(1.0f + __expf(-x));
}

// One block-column per (tensor, group). Each thread owns 4 fixed p-residues.
__global__ __launch_bounds__(TPB) void probs_reduce_kernel(
    const float* __restrict__ ST0, const float* __restrict__ W0,
    const float* __restrict__ ST1, const float* __restrict__ W1,
    const float* __restrict__ BEV, const float* __restrict__ BEVp,
    const float* __restrict__ Bp, float* __restrict__ tmp)
{
    const int t   = threadIdx.x;
    const int tau = blockIdx.y >> 2;   // 0: (ST0,W0)  1: (ST1,W1)
    const int grp = blockIdx.y & 3;

    const float* __restrict__ ST = (tau == 0 ? ST0 : ST1) + grp * M_DIM;
    const float4* __restrict__ W = (const float4*)((tau == 0 ? W0 : W1) + (size_t)grp * NELEM);

    const float B    = Bp[0];
    const float base = fmaxf(BEVp[0], 0.0f) * BEV[0];

    int f = blockIdx.x * TPB + t;

    // invariant residue + incremental m (4*STRIDE divisible by 21)
    int e0 = f * 4;
    int m  = (int)((unsigned)e0 / 21u);
    const int r = e0 - m * 21;                 // 0..20, loop-invariant
    const bool b1 = (r + 1 < 21), b2 = (r + 2 < 21), b3 = (r + 3 < 21);

    float acc0 = 0.f, acc1 = 0.f, acc2 = 0.f, acc3 = 0.f;

    // main loop: 4 independent float4 loads + 8 ST loads in flight per iter
    while (f + 3 * STRIDE < NF4) {
        const float4 wA = W[f];
        const float4 wB = W[f +     STRIDE];
        const float4 wC = W[f + 2 * STRIDE];
        const float4 wD = W[f + 3 * STRIDE];
        const int mA = m, mB = m + DM, mC = m + 2 * DM, mD = m + 3 * DM;
        const float stA0 = ST[mA], stA1 = ST[(mA + 1 < M_DIM) ? mA + 1 : M_DIM - 1];
        const float stB0 = ST[mB], stB1 = ST[(mB + 1 < M_DIM) ? mB + 1 : M_DIM - 1];
        const float stC0 = ST[mC], stC1 = ST[(mC + 1 < M_DIM) ? mC + 1 : M_DIM - 1];
        const float stD0 = ST[mD], stD1 = ST[(mD + 1 < M_DIM) ? mD + 1 : M_DIM - 1];

        float s0, s1;
        s0 = fast_sigmoid(B * (base + stA0)); s1 = fast_sigmoid(B * (base + stA1));
        acc0 += wA.x * s0;
        acc1 += wA.y * (b1 ? s0 : s1);
        acc2 += wA.z * (b2 ? s0 : s1);
        acc3 += wA.w * (b3 ? s0 : s1);
        s0 = fast_sigmoid(B * (base + stB0)); s1 = fast_sigmoid(B * (base + stB1));
        acc0 += wB.x * s0;
        acc1 += wB.y * (b1 ? s0 : s1);
        acc2 += wB.z * (b2 ? s0 : s1);
        acc3 += wB.w * (b3 ? s0 : s1);
        s0 = fast_sigmoid(B * (base + stC0)); s1 = fast_sigmoid(B * (base + stC1));
        acc0 += wC.x * s0;
        acc1 += wC.y * (b1 ? s0 : s1);
        acc2 += wC.z * (b2 ? s0 : s1);
        acc3 += wC.w * (b3 ? s0 : s1);
        s0 = fast_sigmoid(B * (base + stD0)); s1 = fast_sigmoid(B * (base + stD1));
        acc0 += wD.x * s0;
        acc1 += wD.y * (b1 ? s0 : s1);
        acc2 += wD.z * (b2 ? s0 : s1);
        acc3 += wD.w * (b3 ? s0 : s1);

        f += 4 * STRIDE; m += 4 * DM;
    }
    // tail (0 or 1 extra sub-iters per thread)
    while (f < NF4) {
        const float4 w = W[f];
        const int m1 = (m + 1 < M_DIM) ? m + 1 : M_DIM - 1;
        const float s0 = fast_sigmoid(B * (base + ST[m]));
        const float s1 = fast_sigmoid(B * (base + ST[m1]));
        acc0 += w.x * s0;
        acc1 += w.y * (b1 ? s0 : s1);
        acc2 += w.z * (b2 ? s0 : s1);
        acc3 += w.w * (b3 ? s0 : s1);
        f += STRIDE; m += DM;
    }

    // element (t, j) has p = (4t + j) % 21 since 1008 % 21 == 0
    __shared__ float sm[TPB * 4];
    sm[t * 4 + 0] = acc0;
    sm[t * 4 + 1] = acc1;
    sm[t * 4 + 2] = acc2;
    sm[t * 4 + 3] = acc3;
    __syncthreads();

    if (t < NPER) {
        float s = 0.f;
        #pragma unroll
        for (int q = 0; q < (TPB * 4) / NPER; ++q)   // 48 entries per residue
            s += sm[t + NPER * q];
        atomicAdd(&tmp[blockIdx.y * NPER + t], s);
    }
}

__global__ void probs_final_kernel(const float* __restrict__ tmp,
                                   const float* __restrict__ pp,   // (5,4)
                                   float* __restrict__ out)
{
    __shared__ float red[128];
    const int t = threadIdx.x;
    float val = 0.f;
    if (t < 84) {
        const int i = t / 21, inner = t % 21;
        float Pk[5];
        #pragma unroll
        for (int k = 0; k < 5; ++k) {
            float a0 = pp[k*4+0], a1 = pp[k*4+1], a2 = pp[k*4+2], a3 = pp[k*4+3];
            float mx = fmaxf(fmaxf(a0, a1), fmaxf(a2, a3));
            float e0 = __expf(a0-mx), e1 = __expf(a1-mx), e2 = __expf(a2-mx), e3 = __expf(a3-mx);
            float inv = 1.0f / (e0 + e1 + e2 + e3);
            float q0 = e0*inv, q1 = e1*inv, q2 = e2*inv, q3 = e3*inv;
            float q[4] = {q0, q1, q2, q3};
            float v = q[i];
            if (inner > 0) {
                int jj = (inner - 1) / 5, kk = (inner - 1) % 5;
                v *= q[jj];
                if (kk > 0) v *= q[kk - 1];
            }
            Pk[k] = v;
        }
        float t0 = tmp[t], t1 = tmp[84 + t];
        val = Pk[0] * t0 + (Pk[1] + Pk[2] + Pk[3] + Pk[4]) * t1;
    }
    red[t] = val;
    __syncthreads();
    #pragma unroll
    for (int s = 64; s > 0; s >>= 1) {
        if (t < s) red[t] += red[t + s];
        __syncthreads();
    }
    if (t == 0) out[0] = red[0] * 0.2f;   // mean over 5 outs
}

extern "C" void kernel_launch(void* const* d_in, const int* in_sizes, int n_in,
                              void* d_out, int out_size, void* d_ws, size_t ws_size,
                              hipStream_t stream) {
    const float* BEV  = (const float*)d_in[0];
    const float* ST0  = (const float*)d_in[1];
    const float* W0   = (const float*)d_in[2];
    const float* ST1  = (const float*)d_in[3];
    const float* W1   = (const float*)d_in[4];
    const float* pp   = (const float*)d_in[5];
    const float* BEVp = (const float*)d_in[6];
    const float* B    = (const float*)d_in[7];
    float* out = (float*)d_out;
    float* tmp = (float*)d_ws;   // 168 floats: tmp0[84] then tmp1[84]

    hipMemsetAsync(tmp, 0, 168 * sizeof(float), stream);
    probs_reduce_kernel<<<dim3(NBLK, 8), TPB, 0, stream>>>(ST0, W0, ST1, W1,
                                                           BEV, BEVp, B, tmp);
    probs_final_kernel<<<1, 128, 0, stream>>>(tmp, pp, out);
}

// Round 3
// 73.822 us; speedup vs baseline: 1.0333x; 1.0333x over previous
//
#include <hip/hip_runtime.h>
#include <hip/hip_bf16.h>

#define M_DIM   500000
#define NPER    21
#define NELEM   (M_DIM * NPER)          // 10,500,000 floats per (tensor, group)
#define NF4     (NELEM / 4)             // 2,625,000 float4 units
#define NBLK    256
#define TPB     252
#define CH      2                        // float4s per thread-chunk (32 B contiguous)
#define STR_F4  (NBLK * TPB * CH)        // 129,024 f4s per grid pass
#define DM      ((STR_F4 * 4) / 21)      // 24,576  (exact: pass stride divisible by 21)
#define FULLP   20                       // passes 0..19 fully in-bounds for every thread

__device__ __forceinline__ float sig_fast(float st, float k1, float k0) {
    // sigmoid(B*(base+st)) = 1/(1+2^(k1*st+k0)),  k1=-B*log2e, k0=k1*base
    return __builtin_amdgcn_rcpf(1.0f + __builtin_amdgcn_exp2f(fmaf(st, k1, k0)));
}

__global__ __launch_bounds__(TPB) void probs_reduce_kernel(
    const float* __restrict__ ST0, const float* __restrict__ W0,
    const float* __restrict__ ST1, const float* __restrict__ W1,
    const float* __restrict__ BEV, const float* __restrict__ BEVp,
    const float* __restrict__ Bp, float* __restrict__ tmp)
{
    const int t   = threadIdx.x;
    const int tau = blockIdx.y >> 2;   // 0: (ST0,W0)  1: (ST1,W1)
    const int grp = blockIdx.y & 3;

    const float* __restrict__ ST = (tau == 0 ? ST0 : ST1) + grp * M_DIM;
    const float4* __restrict__ W = (const float4*)((tau == 0 ? W0 : W1) + (size_t)grp * NELEM);

    const float B    = Bp[0];
    const float base = fmaxf(BEVp[0], 0.0f) * BEV[0];
    const float k1   = -B * 1.44269504f;
    const float k0   = k1 * base;

    int c0 = (blockIdx.x * TPB + t) * CH;        // f4 index of this thread's chunk
    const int e0 = c0 * 4;
    int m = (int)((unsigned)e0 / 21u);
    const int cthr = 21 - (e0 - m * 21);         // 1..21: elements j<cthr use sig(m), else sig(m+1)

    float a0=0.f,a1=0.f,a2=0.f,a3=0.f,a4=0.f,a5=0.f,a6=0.f,a7=0.f;

    // ---- prologue: load stage 0 ----
    float4 wA = W[c0], wB = W[c0 + 1];
    float  s0 = ST[m];
    int    mp = (m + 1 < M_DIM) ? m + 1 : M_DIM - 1;
    float  s1 = ST[mp];

    #pragma unroll 1
    for (int p = 0; p < FULLP; ++p) {
        // ---- issue next-stage loads (counted-vmcnt pipeline) ----
        const int cn = c0 + STR_F4;
        const int mn = m + DM;
        const bool v = (cn < NF4);               // only pass 19's prefetch can be OOB
        const int cv = v ? cn : 0;
        const int mv = v ? mn : m;
        float4 nA = W[cv], nB = W[cv + 1];
        float  n0 = ST[mv];
        int    mq = (mv + 1 < M_DIM) ? mv + 1 : M_DIM - 1;
        float  n1 = ST[mq];
        __builtin_amdgcn_sched_barrier(0);       // keep prefetch ahead of compute

        // ---- compute current stage ----
        const float g0 = sig_fast(s0, k1, k0);
        const float g1 = sig_fast(s1, k1, k0);
        a0 = fmaf(wA.x, g0, a0);                         // j=0 < cthr always
        a1 = fmaf(wA.y, (1 < cthr) ? g0 : g1, a1);
        a2 = fmaf(wA.z, (2 < cthr) ? g0 : g1, a2);
        a3 = fmaf(wA.w, (3 < cthr) ? g0 : g1, a3);
        a4 = fmaf(wB.x, (4 < cthr) ? g0 : g1, a4);
        a5 = fmaf(wB.y, (5 < cthr) ? g0 : g1, a5);
        a6 = fmaf(wB.z, (6 < cthr) ? g0 : g1, a6);
        a7 = fmaf(wB.w, (7 < cthr) ? g0 : g1, a7);

        // ---- rotate ----
        wA = nA; wB = nB; s0 = n0; s1 = n1; c0 = cn; m = mn;
    }
    // ---- tail stage (chunk-aligned: fully in or fully out) ----
    if (c0 < NF4) {
        const float g0 = sig_fast(s0, k1, k0);
        const float g1 = sig_fast(s1, k1, k0);
        a0 = fmaf(wA.x, g0, a0);
        a1 = fmaf(wA.y, (1 < cthr) ? g0 : g1, a1);
        a2 = fmaf(wA.z, (2 < cthr) ? g0 : g1, a2);
        a3 = fmaf(wA.w, (3 < cthr) ? g0 : g1, a3);
        a4 = fmaf(wB.x, (4 < cthr) ? g0 : g1, a4);
        a5 = fmaf(wB.y, (5 < cthr) ? g0 : g1, a5);
        a6 = fmaf(wB.z, (6 < cthr) ? g0 : g1, a6);
        a7 = fmaf(wB.w, (7 < cthr) ? g0 : g1, a7);
    }

    // element (t, j) has residue (8t + j) % 21; 2016 % 21 == 0 so LDS idx % 21 works
    __shared__ float sm[TPB * 8];
    sm[t*8+0]=a0; sm[t*8+1]=a1; sm[t*8+2]=a2; sm[t*8+3]=a3;
    sm[t*8+4]=a4; sm[t*8+5]=a5; sm[t*8+6]=a6; sm[t*8+7]=a7;
    __syncthreads();

    if (t < NPER) {
        float s = 0.f;
        #pragma unroll
        for (int q = 0; q < (TPB * 8) / NPER; ++q)   // 96 entries per residue
            s += sm[t + NPER * q];
        atomicAdd(&tmp[blockIdx.y * NPER + t], s);
    }
}

__global__ void probs_final_kernel(const float* __restrict__ tmp,
                                   const float* __restrict__ pp,   // (5,4)
                                   float* __restrict__ out)
{
    __shared__ float red[128];
    const int t = threadIdx.x;
    float val = 0.f;
    if (t < 84) {
        const int i = t / 21, inner = t % 21;
        float Pk[5];
        #pragma unroll
        for (int k = 0; k < 5; ++k) {
            float a0 = pp[k*4+0], a1 = pp[k*4+1], a2 = pp[k*4+2], a3 = pp[k*4+3];
            float mx = fmaxf(fmaxf(a0, a1), fmaxf(a2, a3));
            float e0 = __expf(a0-mx), e1 = __expf(a1-mx), e2 = __expf(a2-mx), e3 = __expf(a3-mx);
            float inv = 1.0f / (e0 + e1 + e2 + e3);
            float q[4] = {e0*inv, e1*inv, e2*inv, e3*inv};
            float v = q[i];
            if (inner > 0) {
                int jj = (inner - 1) / 5, kk = (inner - 1) % 5;
                v *= q[jj];
                if (kk > 0) v *= q[kk - 1];
            }
            Pk[k] = v;
        }
        float t0 = tmp[t], t1 = tmp[84 + t];
        val = Pk[0] * t0 + (Pk[1] + Pk[2] + Pk[3] + Pk[4]) * t1;
    }
    red[t] = val;
    __syncthreads();
    #pragma unroll
    for (int s = 64; s > 0; s >>= 1) {
        if (t < s) red[t] += red[t + s];
        __syncthreads();
    }
    if (t == 0) out[0] = red[0] * 0.2f;   // mean over 5 outs
}

extern "C" void kernel_launch(void* const* d_in, const int* in_sizes, int n_in,
                              void* d_out, int out_size, void* d_ws, size_t ws_size,
                              hipStream_t stream) {
    const float* BEV  = (const float*)d_in[0];
    const float* ST0  = (const float*)d_in[1];
    const float* W0   = (const float*)d_in[2];
    const float* ST1  = (const float*)d_in[3];
    const float* W1   = (const float*)d_in[4];
    const float* pp   = (const float*)d_in[5];
    const float* BEVp = (const float*)d_in[6];
    const float* B    = (const float*)d_in[7];
    float* out = (float*)d_out;
    float* tmp = (float*)d_ws;   // 168 floats: tmp0[84] then tmp1[84]

    hipMemsetAsync(tmp, 0, 168 * sizeof(float), stream);
    probs_reduce_kernel<<<dim3(NBLK, 8), TPB, 0, stream>>>(ST0, W0, ST1, W1,
                                                           BEV, BEVp, B, tmp);
    probs_final_kernel<<<1, 128, 0, stream>>>(tmp, pp, out);
}